// Round 11
// baseline (319.347 us; speedup 1.0000x reference)
//
#include <hip/hip_runtime.h>
#include <hip/hip_bf16.h>

typedef __hip_bfloat16 bf16;
typedef __attribute__((ext_vector_type(8))) short bf16x8;
typedef __attribute__((ext_vector_type(4))) float f32x4;

#define MFMA16(a, b, c) __builtin_amdgcn_mfma_f32_16x16x32_bf16(a, b, c, 0, 0, 0)

constexpr int Bc = 2, Tc = 2048, Dc = 1024, Hc = 16, HDc = 64;
constexpr int BTc = Bc * Tc;  // 4096

struct alignas(16) BV8 { bf16 v[8]; };

// ---------------- cast z: fp32 -> bf16, vectorized ----------------
__global__ __launch_bounds__(256)
void cast_f32_to_bf16(const float* __restrict__ in, bf16* __restrict__ out, int n) {
  int i = (blockIdx.x * 256 + threadIdx.x) * 8;
  if (i >= n) return;
  float4 a = *(const float4*)(in + i);
  float4 b = *(const float4*)(in + i + 4);
  BV8 r;
  r.v[0] = __float2bfloat16(a.x); r.v[1] = __float2bfloat16(a.y);
  r.v[2] = __float2bfloat16(a.z); r.v[3] = __float2bfloat16(a.w);
  r.v[4] = __float2bfloat16(b.x); r.v[5] = __float2bfloat16(b.y);
  r.v[6] = __float2bfloat16(b.z); r.v[7] = __float2bfloat16(b.w);
  *(BV8*)(out + i) = r;
}

// ------------- cast + transpose the 4 weights: w[d][e] -> wT[e][d] bf16 -------------
// wq pre-scaled by 0.125*log2(e): attn then uses exp2 directly (exact softmax:
// 2^(s*log2e) = e^s).
__global__ __launch_bounds__(256)
void wT_kernel(const float* __restrict__ w0, const float* __restrict__ w1,
               const float* __restrict__ w2, const float* __restrict__ w3,
               bf16* __restrict__ o0, bf16* __restrict__ o1,
               bf16* __restrict__ o2, bf16* __restrict__ o3) {
  const int which = blockIdx.z;
  const float* src = which == 0 ? w0 : which == 1 ? w1 : which == 2 ? w2 : w3;
  bf16* dst = which == 0 ? o0 : which == 1 ? o1 : which == 2 ? o2 : o3;
  const float scale = (which == 0) ? 0.125f * 1.44269504088896340736f : 1.0f;
  __shared__ float tile[32][33];
  const int tx = threadIdx.x, ty = threadIdx.y;
  const int e0 = blockIdx.x * 32, d0 = blockIdx.y * 32;
#pragma unroll
  for (int rr = 0; rr < 4; ++rr) {
    int r = ty + rr * 8;
    tile[r][tx] = src[(size_t)(d0 + r) * Dc + e0 + tx];
  }
  __syncthreads();
#pragma unroll
  for (int rr = 0; rr < 4; ++rr) {
    int r = ty + rr * 8;
    dst[(size_t)(e0 + r) * Dc + d0 + tx] = __float2bfloat16(tile[tx][r] * scale);
  }
}

// ---------------- GEMM: C[M][N] = A[M][K] * Bt[N][K]^T, bf16 in, CT out ----------------
__device__ inline void store_c(float* p, float v) { *p = v; }
__device__ inline void store_c(bf16* p, float v) { *p = __float2bfloat16(v); }

template <typename CT>
__global__ __launch_bounds__(256)
void gemm_bt_kernel(const bf16* __restrict__ A, const bf16* __restrict__ Bt,
                    CT* __restrict__ C, int M, int N, int K) {
  __shared__ bf16 As[128 * 32];
  __shared__ bf16 Bs[128 * 32];
  const int t = threadIdx.x;
  const int lane = t & 63, w = t >> 6;
  const int wr = w >> 1, wc = w & 1;
  const int m0 = blockIdx.y * 128, n0 = blockIdx.x * 128;
  const int l15 = lane & 15, l4 = lane >> 4;
  const int srow = lane >> 2;
  const int scol = (lane & 3) * 8;

  f32x4 acc[4][4] = {};

  for (int k0 = 0; k0 < K; k0 += 32) {
#pragma unroll
    for (int j = 0; j < 2; ++j) {
      const int ch = j * 4 + w;
      const int row = ch * 16 + srow;
      __builtin_amdgcn_global_load_lds(
          (const __attribute__((address_space(1))) void*)(A + (size_t)(m0 + row) * K + k0 + scol),
          (__attribute__((address_space(3))) void*)(As + ch * 512), 16, 0, 0);
      __builtin_amdgcn_global_load_lds(
          (const __attribute__((address_space(1))) void*)(Bt + (size_t)(n0 + row) * K + k0 + scol),
          (__attribute__((address_space(3))) void*)(Bs + ch * 512), 16, 0, 0);
    }
    __syncthreads();

    bf16x8 af[4], bg[4];
#pragma unroll
    for (int m = 0; m < 4; ++m)
      af[m] = *(const bf16x8*)(As + (wr * 64 + m * 16 + l15) * 32 + l4 * 8);
#pragma unroll
    for (int n = 0; n < 4; ++n)
      bg[n] = *(const bf16x8*)(Bs + (wc * 64 + n * 16 + l15) * 32 + l4 * 8);
#pragma unroll
    for (int m = 0; m < 4; ++m)
#pragma unroll
      for (int n = 0; n < 4; ++n)
        acc[m][n] = MFMA16(af[m], bg[n], acc[m][n]);
    __syncthreads();
  }

#pragma unroll
  for (int m = 0; m < 4; ++m) {
    const int row = m0 + wr * 64 + m * 16 + l4 * 4;
#pragma unroll
    for (int n = 0; n < 4; ++n) {
      const int col = n0 + wc * 64 + n * 16 + l15;
#pragma unroll
      for (int r = 0; r < 4; ++r)
        store_c(&C[(size_t)(row + r) * N + col], acc[m][n][r]);
    }
  }
}

// ---------------- causal flash attention: paired q-tiles + kv-split 2 ----------------
// grid (16, 32, 2). Block (lo, bh, zh): q-tiles lo and hi=31-lo of head bh, kv chunks
// [c0,c1) where split S balances units 16/17 per half. No-max exp2 softmax => partials
// combine by pure addition (separate combine kernel). LDS = 40960B => 4 blocks/CU,
// 1024 blocks = one full residency round. P buffer [16][64] per wave, XOR-swizzled
// (off ^= (q&7)<<4 on both write and read sides).
__global__ __launch_bounds__(256, 4)
void attn_kernel(const bf16* __restrict__ Q, const bf16* __restrict__ Kg, int ldqk,
                 const bf16* __restrict__ Vt, bf16* __restrict__ pc0,
                 bf16* __restrict__ pc1, float* __restrict__ pd0,
                 float* __restrict__ pd1) {
  const int t = threadIdx.x;
  const int lane = t & 63, w = t >> 6;
  const int l15 = lane & 15, l4 = lane >> 4;
  const int bh = blockIdx.y, b = bh >> 4, h = bh & 15;
  const int lo = blockIdx.x, hi = 31 - lo;
  const int zh = blockIdx.z;
  const int nch = hi + 1;
  const int S = (lo >= 8) ? 8 : (16 - lo);
  const int c0 = zh ? S : 0;
  const int c1 = zh ? nch : S;
  const int qlo = lo * 64 + w * 16;
  const int qhi = hi * 64 + w * 16;

  __shared__ bf16 Ks[2][64 * 64];   // 16 KB
  __shared__ bf16 Vs[2][64 * 64];   // 16 KB
  __shared__ bf16 P[4][16 * 64];    //  8 KB -> total 40960 B

  const int srow_in = lane >> 3;    // 0..7 within 8-row unit
  const int scb = lane & 7;         // 16B column block

  // Q A-fragments for both tiles (registers for whole loop); Q pre-scaled 0.125*log2e
  const bf16* qph = Q + (size_t)(b * Tc + qhi + l15) * ldqk + h * HDc + l4 * 8;
  const bf16x8 ah0 = *(const bf16x8*)(qph);
  const bf16x8 ah1 = *(const bf16x8*)(qph + 32);
  const bf16* qpl = Q + (size_t)(b * Tc + qlo + l15) * ldqk + h * HDc + l4 * 8;
  const bf16x8 al0 = *(const bf16x8*)(qpl);
  const bf16x8 al1 = *(const bf16x8*)(qpl + 32);

  f32x4 ch[4] = {}, cl[4] = {};
  float shr = 0.0f, slr = 0.0f;

  char* Pw = (char*)&P[w][0];
  const int pswz = (l15 & 7) << 4;

  auto stage = [&](int buf, int c) {
    const int kv0 = c * 64;
#pragma unroll
    for (int i = 0; i < 4; ++i) {
      const int u = w * 4 + i;          // 0..15; 0-7 -> K, 8-15 -> V
      const int ul = u & 7;
      const int row = ul * 8 + srow_in;
      const int cbs = scb ^ (row & 7);  // inverse-swizzled SOURCE col block
      if (u < 8) {
        const bf16* src = Kg + (size_t)(b * Tc + kv0 + row) * ldqk + h * HDc + cbs * 8;
        __builtin_amdgcn_global_load_lds(
            (const __attribute__((address_space(1))) void*)src,
            (__attribute__((address_space(3))) void*)(Ks[buf] + ul * 512), 16, 0, 0);
      } else {
        const bf16* src = Vt + (size_t)(h * HDc + row) * BTc + b * Tc + kv0 + cbs * 8;
        __builtin_amdgcn_global_load_lds(
            (const __attribute__((address_space(1))) void*)src,
            (__attribute__((address_space(3))) void*)(Vs[buf] + ul * 512), 16, 0, 0);
      }
    }
  };

  // S^T = K * Q^T (swapped operands): lane (l15,l4) -> S[q=l15][kv=n*16+l4*4+r]
  auto qk = [&](const bf16* Kbuf, const bf16x8& a0, const bf16x8& a1, f32x4* s) {
#pragma unroll
    for (int n = 0; n < 4; ++n) {
      const int row = n * 16 + l15;
      const bf16* kr = Kbuf + row * 64;
      bf16x8 bk0 = *(const bf16x8*)(kr + ((l4 ^ (row & 7)) << 3));
      bf16x8 bk1 = *(const bf16x8*)(kr + (((4 + l4) ^ (row & 7)) << 3));
      f32x4 zz = {};
      zz = MFMA16(bk0, a0, zz);
      s[n] = MFMA16(bk1, a1, zz);
    }
  };

  // exp2 + packed swizzled P write + scalar running denom
  auto expP = [&](f32x4* s, float& srun, int kv0, int qb, bool mask) {
    const int q = qb + l15;
#pragma unroll
    for (int n = 0; n < 4; ++n) {
      float e[4];
#pragma unroll
      for (int r = 0; r < 4; ++r) {
        float v = __builtin_amdgcn_exp2f(s[n][r]);
        if (mask) {
          const int kv = kv0 + n * 16 + l4 * 4 + r;
          v = (kv <= q) ? v : 0.0f;
        }
        e[r] = v;
        srun += v;
      }
      unsigned u0, u1;
      asm("v_cvt_pk_bf16_f32 %0, %1, %2" : "=v"(u0) : "v"(e[0]), "v"(e[1]));
      asm("v_cvt_pk_bf16_f32 %0, %1, %2" : "=v"(u1) : "v"(e[2]), "v"(e[3]));
      uint2 uu; uu.x = u0; uu.y = u1;
      *(uint2*)(Pw + l15 * 128 + ((n * 32 + l4 * 8) ^ pswz)) = uu;
    }
  };

  auto pv = [&](const bf16* Vbuf, f32x4* ctx) {
    const bf16x8 pa0 = *(const bf16x8*)(Pw + l15 * 128 + ((l4 * 16) ^ pswz));
    const bf16x8 pa1 = *(const bf16x8*)(Pw + l15 * 128 + ((64 + l4 * 16) ^ pswz));
#pragma unroll
    for (int dn = 0; dn < 4; ++dn) {
      const int row = dn * 16 + l15;
      const bf16* vr = Vbuf + row * 64;
      bf16x8 bv0 = *(const bf16x8*)(vr + ((l4 ^ (row & 7)) << 3));
      bf16x8 bv1 = *(const bf16x8*)(vr + (((4 + l4) ^ (row & 7)) << 3));
      ctx[dn] = MFMA16(pa0, bv0, ctx[dn]);
      ctx[dn] = MFMA16(pa1, bv1, ctx[dn]);
    }
  };

  stage(0, c0);
  __syncthreads();
  int par = 0;
  for (int c = c0; c < c1; ++c) {
    if (c + 1 < c1) stage(par ^ 1, c + 1);
    f32x4 s4[4];
    // hi tile (single shared P buffer: chain hi fully, then lo)
    qk(Ks[par], ah0, ah1, s4);
    expP(s4, shr, c * 64, qhi, c == hi);
    pv(Vs[par], ch);
    if (c <= lo) {
      qk(Ks[par], al0, al1, s4);
      expP(s4, slr, c * 64, qlo, c == lo);
      pv(Vs[par], cl);
    }
    __syncthreads();   // drains vmcnt (prefetch done) + protects buffer swap
    par ^= 1;
  }

  // partial denominators for q = tile_base + l15 (sum over this half's chunks)
  shr += __shfl_xor(shr, 16); shr += __shfl_xor(shr, 32);
  slr += __shfl_xor(slr, 16); slr += __shfl_xor(slr, 32);

  bf16* pco = zh ? pc1 : pc0;
  float* pdo = zh ? pd1 : pd0;
#pragma unroll
  for (int dn = 0; dn < 4; ++dn)
#pragma unroll
    for (int r = 0; r < 4; ++r) {
      pco[(size_t)(b * Tc + qhi + l4 * 4 + r) * Dc + h * HDc + dn * 16 + l15] =
          __float2bfloat16(ch[dn][r]);
      pco[(size_t)(b * Tc + qlo + l4 * 4 + r) * Dc + h * HDc + dn * 16 + l15] =
          __float2bfloat16(cl[dn][r]);   // zeros when this half never touched lo-tile
    }
  if (l4 == 0) {
    pdo[(size_t)(b * Tc + qhi + l15) * Hc + h] = shr;
    pdo[(size_t)(b * Tc + qlo + l15) * Hc + h] = slr;
  }
}

// ---------------- combine: Ctx = (pcA + pcB) / (dA + dB) ----------------
__global__ __launch_bounds__(256)
void combine_kernel(const bf16* __restrict__ pcA, const bf16* __restrict__ pcB,
                    const float* __restrict__ pdA, const float* __restrict__ pdB,
                    bf16* __restrict__ out) {
  const int i = blockIdx.x * 256 + threadIdx.x;  // one 8-wide group per thread
  const int row = i >> 7;                        // 128 groups of 8 per 1024-col row
  const int g = i & 127;
  const int h = g >> 3;                          // 8 groups per 64-col head
  const float invd = 1.0f / (pdA[(size_t)row * Hc + h] + pdB[(size_t)row * Hc + h]);
  bf16x8 a = *(const bf16x8*)(pcA + (size_t)i * 8);
  bf16x8 b = *(const bf16x8*)(pcB + (size_t)i * 8);
  BV8 o;
#pragma unroll
  for (int j = 0; j < 8; ++j) {
    float va = __bfloat162float(((const bf16*)&a)[j]);
    float vb = __bfloat162float(((const bf16*)&b)[j]);
    o.v[j] = __float2bfloat16((va + vb) * invd);
  }
  *(BV8*)(out + (size_t)i * 8) = o;
}

// ---------------- launcher ----------------
extern "C" void kernel_launch(void* const* d_in, const int* in_sizes, int n_in,
                              void* d_out, int out_size, void* d_ws, size_t ws_size,
                              hipStream_t stream) {
  const float* z  = (const float*)d_in[0];
  const float* wq = (const float*)d_in[1];
  const float* wk = (const float*)d_in[2];
  const float* wv = (const float*)d_in[3];
  const float* wo = (const float*)d_in[4];
  float* out = (float*)d_out;

  char* ws = (char*)d_ws;
  const size_t MB = 1ull << 20;
  // 48MB total via lifetime overlays:
  //   [0,8)   zb  -> pc0 (zb dead after V-GEMM; attn writes pc0 after)
  //   [8,12)  wqT,wkT -> pd0,pd1 (dead after QK-GEMM)
  //   [12,14) wvT (dead after V-GEMM)
  //   [14,16) woT (live until O-GEMM)
  //   [16,32) QK -> Ctx@[16,24) (QK dead after attn; combine writes Ctx after)
  //   [32,40) Vtb (dead after attn)
  //   [40,48) pc1
  bf16* zb  = (bf16*)(ws + 0 * MB);
  bf16* wqT = (bf16*)(ws + 8 * MB);    // wqT/wkT contiguous => one Bt[2048][1024]
  bf16* wkT = (bf16*)(ws + 10 * MB);
  bf16* wvT = (bf16*)(ws + 12 * MB);
  bf16* woT = (bf16*)(ws + 14 * MB);
  bf16* QK  = (bf16*)(ws + 16 * MB);   // [4096][2048]: Q cols 0..1023, K cols 1024..2047
  bf16* Vtb = (bf16*)(ws + 32 * MB);   // [1024][4096] (V transposed)
  bf16* pc0 = (bf16*)(ws + 0 * MB);    // partial ctx half A [4096][1024] bf16, 8MB
  bf16* pc1 = (bf16*)(ws + 40 * MB);   // partial ctx half B, 8MB
  float* pd0 = (float*)(ws + 8 * MB);  // partial denom A [4096][16] f32, 256KB
  float* pd1 = (float*)(ws + 9 * MB);  // partial denom B
  bf16* Ctx = (bf16*)(ws + 16 * MB);   // [4096][1024] (overlays dead QK)

  cast_f32_to_bf16<<<dim3(2048), dim3(256), 0, stream>>>(z, zb, Bc * Tc * Dc);
  wT_kernel<<<dim3(32, 32, 4), dim3(32, 8), 0, stream>>>(wq, wk, wv, wo, wqT, wkT, wvT, woT);

  // [Q|K] = z @ [wq|wk] : one GEMM, N=2048
  gemm_bt_kernel<bf16><<<dim3(16, 32), dim3(256), 0, stream>>>(zb, wqT, QK, 4096, 2048, 1024);
  // V^T[e][t] = sum_d wv[d][e] z[t][d]
  gemm_bt_kernel<bf16><<<dim3(32, 8), dim3(256), 0, stream>>>(wvT, zb, Vtb, 1024, 4096, 1024);

  attn_kernel<<<dim3(16, 32, 2), dim3(256), 0, stream>>>(QK, QK + 1024, 2048, Vtb,
                                                         pc0, pc1, pd0, pd1);
  combine_kernel<<<dim3(2048), dim3(256), 0, stream>>>(pc0, pc1, pd0, pd1, Ctx);

  // out = ctx @ wo (fp32 out)
  gemm_bt_kernel<float><<<dim3(8, 32), dim3(256), 0, stream>>>(Ctx, woT, out, 4096, 1024, 1024);
}

// Round 15
// 188.902 us; speedup vs baseline: 1.6905x; 1.6905x over previous
//
#include <hip/hip_runtime.h>
#include <hip/hip_bf16.h>

typedef __hip_bfloat16 bf16;
typedef __attribute__((ext_vector_type(8))) short bf16x8;
typedef __attribute__((ext_vector_type(4))) float f32x4;

#define MFMA16(a, b, c) __builtin_amdgcn_mfma_f32_16x16x32_bf16(a, b, c, 0, 0, 0)

constexpr int Bc = 2, Tc = 2048, Dc = 1024, Hc = 16, HDc = 64;
constexpr int BTc = Bc * Tc;  // 4096

struct alignas(16) BV8 { bf16 v[8]; };

// ---------------- cast z: fp32 -> bf16, vectorized ----------------
__global__ __launch_bounds__(256)
void cast_f32_to_bf16(const float* __restrict__ in, bf16* __restrict__ out, int n) {
  int i = (blockIdx.x * 256 + threadIdx.x) * 8;
  if (i >= n) return;
  float4 a = *(const float4*)(in + i);
  float4 b = *(const float4*)(in + i + 4);
  BV8 r;
  r.v[0] = __float2bfloat16(a.x); r.v[1] = __float2bfloat16(a.y);
  r.v[2] = __float2bfloat16(a.z); r.v[3] = __float2bfloat16(a.w);
  r.v[4] = __float2bfloat16(b.x); r.v[5] = __float2bfloat16(b.y);
  r.v[6] = __float2bfloat16(b.z); r.v[7] = __float2bfloat16(b.w);
  *(BV8*)(out + i) = r;
}

// ------------- cast + transpose the 4 weights: w[d][e] -> wT[e][d] bf16 -------------
// wq pre-scaled by 0.125*log2(e): attn uses exp2 directly (2^(s*log2e) = e^s, exact).
__global__ __launch_bounds__(256)
void wT_kernel(const float* __restrict__ w0, const float* __restrict__ w1,
               const float* __restrict__ w2, const float* __restrict__ w3,
               bf16* __restrict__ o0, bf16* __restrict__ o1,
               bf16* __restrict__ o2, bf16* __restrict__ o3) {
  const int which = blockIdx.z;
  const float* src = which == 0 ? w0 : which == 1 ? w1 : which == 2 ? w2 : w3;
  bf16* dst = which == 0 ? o0 : which == 1 ? o1 : which == 2 ? o2 : o3;
  const float scale = (which == 0) ? 0.125f * 1.44269504088896340736f : 1.0f;
  __shared__ float tile[32][33];
  const int tx = threadIdx.x, ty = threadIdx.y;
  const int e0 = blockIdx.x * 32, d0 = blockIdx.y * 32;
#pragma unroll
  for (int rr = 0; rr < 4; ++rr) {
    int r = ty + rr * 8;
    tile[r][tx] = src[(size_t)(d0 + r) * Dc + e0 + tx];
  }
  __syncthreads();
#pragma unroll
  for (int rr = 0; rr < 4; ++rr) {
    int r = ty + rr * 8;
    dst[(size_t)(e0 + r) * Dc + d0 + tx] = __float2bfloat16(tile[tx][r] * scale);
  }
}

// ---------------- V transpose: QKV V-cols [4096][ld 3072] -> Vt[1024][4096] ----------------
__global__ __launch_bounds__(256)
void vT_kernel(const bf16* __restrict__ src, bf16* __restrict__ dst) {
  __shared__ bf16 tile[32][33];
  const int tx = threadIdx.x, ty = threadIdx.y;   // (32, 8)
  const int e0 = blockIdx.x * 32;                 // 32 blocks over e=1024
  const int t0 = blockIdx.y * 32;                 // 128 blocks over t=4096
#pragma unroll
  for (int rr = 0; rr < 4; ++rr) {
    int r = ty + rr * 8;
    tile[r][tx] = src[(size_t)(t0 + r) * 3072 + e0 + tx];
  }
  __syncthreads();
#pragma unroll
  for (int rr = 0; rr < 4; ++rr) {
    int r = ty + rr * 8;
    dst[(size_t)(e0 + r) * (size_t)BTc + t0 + tx] = tile[tx][r];
  }
}

// ---------------- GEMM: C[M][N] = A[M][K] * Bt[N][K]^T, bf16 in, CT out ----------------
__device__ inline void store_c(float* p, float v) { *p = v; }
__device__ inline void store_c(bf16* p, float v) { *p = __float2bfloat16(v); }

template <typename CT>
__global__ __launch_bounds__(256)
void gemm_bt_kernel(const bf16* __restrict__ A, const bf16* __restrict__ Bt,
                    CT* __restrict__ C, int M, int N, int K) {
  __shared__ bf16 As[128 * 32];
  __shared__ bf16 Bs[128 * 32];
  const int t = threadIdx.x;
  const int lane = t & 63, w = t >> 6;
  const int wr = w >> 1, wc = w & 1;
  const int m0 = blockIdx.y * 128, n0 = blockIdx.x * 128;
  const int l15 = lane & 15, l4 = lane >> 4;
  const int srow = lane >> 2;
  const int scol = (lane & 3) * 8;

  f32x4 acc[4][4] = {};

  for (int k0 = 0; k0 < K; k0 += 32) {
#pragma unroll
    for (int j = 0; j < 2; ++j) {
      const int ch = j * 4 + w;
      const int row = ch * 16 + srow;
      __builtin_amdgcn_global_load_lds(
          (const __attribute__((address_space(1))) void*)(A + (size_t)(m0 + row) * K + k0 + scol),
          (__attribute__((address_space(3))) void*)(As + ch * 512), 16, 0, 0);
      __builtin_amdgcn_global_load_lds(
          (const __attribute__((address_space(1))) void*)(Bt + (size_t)(n0 + row) * K + k0 + scol),
          (__attribute__((address_space(3))) void*)(Bs + ch * 512), 16, 0, 0);
    }
    __syncthreads();

    bf16x8 af[4], bg[4];
#pragma unroll
    for (int m = 0; m < 4; ++m)
      af[m] = *(const bf16x8*)(As + (wr * 64 + m * 16 + l15) * 32 + l4 * 8);
#pragma unroll
    for (int n = 0; n < 4; ++n)
      bg[n] = *(const bf16x8*)(Bs + (wc * 64 + n * 16 + l15) * 32 + l4 * 8);
#pragma unroll
    for (int m = 0; m < 4; ++m)
#pragma unroll
      for (int n = 0; n < 4; ++n)
        acc[m][n] = MFMA16(af[m], bg[n], acc[m][n]);
    __syncthreads();
  }

#pragma unroll
  for (int m = 0; m < 4; ++m) {
    const int row = m0 + wr * 64 + m * 16 + l4 * 4;
#pragma unroll
    for (int n = 0; n < 4; ++n) {
      const int col = n0 + wc * 64 + n * 16 + l15;
#pragma unroll
      for (int r = 0; r < 4; ++r)
        store_c(&C[(size_t)(row + r) * N + col], acc[m][n][r]);
    }
  }
}

// ---------------- causal flash attention: paired q-tiles (single kernel) ----------------
// Block (lo, bh): q-tiles lo and hi=31-lo; 33 chunk-units/block (perfect balance);
// all blocks stream chunks from 0 in lockstep => K/V L2 temporal locality (round-11
// lesson: staggered streams destroy it). Swapped QK^T, exp2 no-max softmax, shared
// per-wave P[16][64] XOR-swizzled. LDS 40960B. Grid 512 = 2 blocks/CU.
__global__ __launch_bounds__(256)
void attn_kernel(const bf16* __restrict__ Q, const bf16* __restrict__ Kg, int ldqk,
                 const bf16* __restrict__ Vt, bf16* __restrict__ O) {
  const int t = threadIdx.x;
  const int lane = t & 63, w = t >> 6;
  const int l15 = lane & 15, l4 = lane >> 4;
  const int bh = blockIdx.y, b = bh >> 4, h = bh & 15;
  const int lo = blockIdx.x, hi = 31 - lo;
  const int nch = hi + 1;
  const int qlo = lo * 64 + w * 16;
  const int qhi = hi * 64 + w * 16;

  __shared__ bf16 Ks[2][64 * 64];   // 16 KB
  __shared__ bf16 Vs[2][64 * 64];   // 16 KB
  __shared__ bf16 P[4][16 * 64];    //  8 KB -> 40960 B total

  const int srow_in = lane >> 3;
  const int scb = lane & 7;

  const bf16* qph = Q + (size_t)(b * Tc + qhi + l15) * ldqk + h * HDc + l4 * 8;
  const bf16x8 ah0 = *(const bf16x8*)(qph);
  const bf16x8 ah1 = *(const bf16x8*)(qph + 32);
  const bf16* qpl = Q + (size_t)(b * Tc + qlo + l15) * ldqk + h * HDc + l4 * 8;
  const bf16x8 al0 = *(const bf16x8*)(qpl);
  const bf16x8 al1 = *(const bf16x8*)(qpl + 32);

  f32x4 ch[4] = {}, cl[4] = {};
  float shr = 0.0f, slr = 0.0f;

  char* Pw = (char*)&P[w][0];
  const int pswz = (l15 & 7) << 4;

  auto stage = [&](int buf, int c) {
    const int kv0 = c * 64;
#pragma unroll
    for (int i = 0; i < 4; ++i) {
      const int u = w * 4 + i;
      const int ul = u & 7;
      const int row = ul * 8 + srow_in;
      const int cbs = scb ^ (row & 7);
      if (u < 8) {
        const bf16* src = Kg + (size_t)(b * Tc + kv0 + row) * ldqk + h * HDc + cbs * 8;
        __builtin_amdgcn_global_load_lds(
            (const __attribute__((address_space(1))) void*)src,
            (__attribute__((address_space(3))) void*)(Ks[buf] + ul * 512), 16, 0, 0);
      } else {
        const bf16* src = Vt + (size_t)(h * HDc + row) * BTc + b * Tc + kv0 + cbs * 8;
        __builtin_amdgcn_global_load_lds(
            (const __attribute__((address_space(1))) void*)src,
            (__attribute__((address_space(3))) void*)(Vs[buf] + ul * 512), 16, 0, 0);
      }
    }
  };

  auto qk = [&](const bf16* Kbuf, const bf16x8& a0, const bf16x8& a1, f32x4* s) {
#pragma unroll
    for (int n = 0; n < 4; ++n) {
      const int row = n * 16 + l15;
      const bf16* kr = Kbuf + row * 64;
      bf16x8 bk0 = *(const bf16x8*)(kr + ((l4 ^ (row & 7)) << 3));
      bf16x8 bk1 = *(const bf16x8*)(kr + (((4 + l4) ^ (row & 7)) << 3));
      f32x4 zz = {};
      zz = MFMA16(bk0, a0, zz);
      s[n] = MFMA16(bk1, a1, zz);
    }
  };

  auto expP = [&](f32x4* s, float& srun, int kv0, int qb, bool mask) {
    const int q = qb + l15;
#pragma unroll
    for (int n = 0; n < 4; ++n) {
      float e[4];
#pragma unroll
      for (int r = 0; r < 4; ++r) {
        float v = __builtin_amdgcn_exp2f(s[n][r]);
        if (mask) {
          const int kv = kv0 + n * 16 + l4 * 4 + r;
          v = (kv <= q) ? v : 0.0f;
        }
        e[r] = v;
        srun += v;
      }
      unsigned u0, u1;
      asm("v_cvt_pk_bf16_f32 %0, %1, %2" : "=v"(u0) : "v"(e[0]), "v"(e[1]));
      asm("v_cvt_pk_bf16_f32 %0, %1, %2" : "=v"(u1) : "v"(e[2]), "v"(e[3]));
      uint2 uu; uu.x = u0; uu.y = u1;
      *(uint2*)(Pw + l15 * 128 + ((n * 32 + l4 * 8) ^ pswz)) = uu;
    }
  };

  auto pv = [&](const bf16* Vbuf, f32x4* ctx) {
    const bf16x8 pa0 = *(const bf16x8*)(Pw + l15 * 128 + ((l4 * 16) ^ pswz));
    const bf16x8 pa1 = *(const bf16x8*)(Pw + l15 * 128 + ((64 + l4 * 16) ^ pswz));
#pragma unroll
    for (int dn = 0; dn < 4; ++dn) {
      const int row = dn * 16 + l15;
      const bf16* vr = Vbuf + row * 64;
      bf16x8 bv0 = *(const bf16x8*)(vr + ((l4 ^ (row & 7)) << 3));
      bf16x8 bv1 = *(const bf16x8*)(vr + (((4 + l4) ^ (row & 7)) << 3));
      ctx[dn] = MFMA16(pa0, bv0, ctx[dn]);
      ctx[dn] = MFMA16(pa1, bv1, ctx[dn]);
    }
  };

  stage(0, 0);
  __syncthreads();
  int par = 0;
  for (int c = 0; c < nch; ++c) {
    if (c + 1 < nch) stage(par ^ 1, c + 1);
    f32x4 s4[4];
    qk(Ks[par], ah0, ah1, s4);          // hi tile chain (shared P buffer)
    expP(s4, shr, c * 64, qhi, c == hi);
    pv(Vs[par], ch);
    if (c <= lo) {                      // lo tile chain
      qk(Ks[par], al0, al1, s4);
      expP(s4, slr, c * 64, qlo, c == lo);
      pv(Vs[par], cl);
    }
    __syncthreads();
    par ^= 1;
  }

  // denominators for q = tile_base + l15, then redistribute to ctx rows (q = l4*4+r)
  shr += __shfl_xor(shr, 16); shr += __shfl_xor(shr, 32);
  slr += __shfl_xor(slr, 16); slr += __shfl_xor(slr, 32);
  float ihr[4], ilr[4];
#pragma unroll
  for (int r = 0; r < 4; ++r) {
    ihr[r] = 1.0f / __shfl(shr, l4 * 4 + r);
    ilr[r] = 1.0f / __shfl(slr, l4 * 4 + r);
  }
#pragma unroll
  for (int dn = 0; dn < 4; ++dn)
#pragma unroll
    for (int r = 0; r < 4; ++r) {
      O[(size_t)(b * Tc + qhi + l4 * 4 + r) * Dc + h * HDc + dn * 16 + l15] =
          __float2bfloat16(ch[dn][r] * ihr[r]);
      O[(size_t)(b * Tc + qlo + l4 * 4 + r) * Dc + h * HDc + dn * 16 + l15] =
          __float2bfloat16(cl[dn][r] * ilr[r]);
    }
}

// ---------------- launcher ----------------
extern "C" void kernel_launch(void* const* d_in, const int* in_sizes, int n_in,
                              void* d_out, int out_size, void* d_ws, size_t ws_size,
                              hipStream_t stream) {
  const float* z  = (const float*)d_in[0];
  const float* wq = (const float*)d_in[1];
  const float* wk = (const float*)d_in[2];
  const float* wv = (const float*)d_in[3];
  const float* wo = (const float*)d_in[4];
  float* out = (float*)d_out;

  char* ws = (char*)d_ws;
  const size_t MB = 1ull << 20;
  // 48MB layout:
  //   [0,8)   zb (dead after QKV-GEMM) -> Ctx overlay
  //   [8,14)  wqkvT [3072][1024] (wq scaled, wk, wv contiguous)
  //   [14,16) woT (live until O-GEMM)
  //   [16,40) QKV [4096][3072]: Q cols 0..1023, K 1024..2047, V 2048..3071
  //   [40,48) Vtb [1024][4096]
  bf16* zb    = (bf16*)(ws + 0 * MB);
  bf16* wqkvT = (bf16*)(ws + 8 * MB);
  bf16* woT   = (bf16*)(ws + 14 * MB);
  bf16* QKV   = (bf16*)(ws + 16 * MB);
  bf16* Vtb   = (bf16*)(ws + 40 * MB);
  bf16* Ctx   = (bf16*)(ws + 0 * MB);

  cast_f32_to_bf16<<<dim3(2048), dim3(256), 0, stream>>>(z, zb, Bc * Tc * Dc);
  wT_kernel<<<dim3(32, 32, 4), dim3(32, 8), 0, stream>>>(
      wq, wk, wv, wo,
      wqkvT, wqkvT + (size_t)1024 * Dc, wqkvT + (size_t)2048 * Dc, woT);

  // [Q|K|V] = z @ [wq|wk|wv] : one GEMM, N=3072, grid 768 blocks (3/CU)
  gemm_bt_kernel<bf16><<<dim3(24, 32), dim3(256), 0, stream>>>(zb, wqkvT, QKV, 4096, 3072, 1024);
  // V^T via LDS transpose (~3 us)
  vT_kernel<<<dim3(32, 128), dim3(32, 8), 0, stream>>>(QKV + 2048, Vtb);

  attn_kernel<<<dim3(16, 32), dim3(256), 0, stream>>>(QKV, QKV + 1024, 3072, Vtb, Ctx);

  // out = ctx @ wo (fp32 out)
  gemm_bt_kernel<float><<<dim3(8, 32), dim3(256), 0, stream>>>(Ctx, woT, out, 4096, 1024, 1024);
}